// Round 7
// baseline (714.839 us; speedup 1.0000x reference)
//
#include <hip/hip_runtime.h>
#include <math.h>

#define Bb 32
#define Nn 2048
#define Dd 512
#define NS 8
#define ITERS 3
#define EPSf 1e-8f
#define SCALEf 0.04419417382415922f   // 512^-0.5
#define LN_EPSf 1e-5f

#define CHUNKS 16  // attention token chunks (128 tokens each)
#define SUBT 32    // tokens per attn sub-tile

typedef _Float16 half8 __attribute__((ext_vector_type(8)));
typedef _Float16 half2v __attribute__((ext_vector_type(2)));
typedef float f32x4 __attribute__((ext_vector_type(4)));

__device__ __forceinline__ float waveReduceSum(float v) {
    #pragma unroll
    for (int m = 32; m >= 1; m >>= 1) v += __shfl_xor(v, m);
    return v;
}

__device__ __forceinline__ float gelu_exact(float x) {
    return 0.5f * x * (1.0f + erff(x * 0.7071067811865476f));
}

__device__ __forceinline__ void async_copy16(const _Float16* g, _Float16* l) {
    __builtin_amdgcn_global_load_lds(
        (const __attribute__((address_space(1))) unsigned int*)g,
        (__attribute__((address_space(3))) unsigned int*)l, 16, 0, 0);
}

// ================= pack kernels =================
// mode dup: B rows stored [n][K | K] (value duplicated) — for hi|lo-A gemms.
// mode hilo (w_ih only): [m][K=hi | K=residual] — A-operand for the Mih prep gemm.
__global__ __launch_bounds__(256) void megapack_kernel(
    const float* __restrict__ w_ih, const float* __restrict__ w_hh,
    const float* __restrict__ m1, const float* __restrict__ m2,
    const float* __restrict__ m3, const float* __restrict__ m4,
    const float* __restrict__ v_w,
    _Float16* __restrict__ Aih, _Float16* __restrict__ Bhh,
    _Float16* __restrict__ Bm1, _Float16* __restrict__ Bm2,
    _Float16* __restrict__ Bm3, _Float16* __restrict__ Bm4,
    _Float16* __restrict__ Bvd) {
    int bid = blockIdx.x, tid = threadIdx.x;
    const float* src; _Float16* dst; int kbits, base, hilo = 0;
    if      (bid < 3072)  { src = w_ih; dst = Aih; kbits = 9;  base = 0; hilo = 1; }
    else if (bid < 6144)  { src = w_hh; dst = Bhh; kbits = 9;  base = 3072; }
    else if (bid < 8192)  { src = m1;   dst = Bm1; kbits = 9;  base = 6144; }
    else if (bid < 12288) { src = m2;   dst = Bm2; kbits = 10; base = 8192; }
    else if (bid < 14336) { src = m3;   dst = Bm3; kbits = 10; base = 12288; }
    else if (bid < 14848) { src = m4;   dst = Bm4; kbits = 9;  base = 14336; }
    else                  { src = v_w;  dst = Bvd; kbits = 9;  base = 14848; }
    int e = (bid - base) * 256 + tid;
    int K = 1 << kbits;
    int row = e >> kbits, k = e & (K - 1);
    float v = src[e];
    _Float16 hi = (_Float16)v;
    _Float16* d = dst + ((size_t)row << (kbits + 1));
    d[k] = hi;
    d[K + k] = hilo ? (_Float16)(v - (float)hi) : hi;
}

// z=0: BkT[d][f] = k_w[f][d] fp16 flat [512][512]
// z=1: BvT[d][n | n] = v_w[n][d] fp16 dup [512][1024]
__global__ __launch_bounds__(256) void twk_kernel(
    const float* __restrict__ kw, const float* __restrict__ vw,
    _Float16* __restrict__ BkT, _Float16* __restrict__ BvT) {
    __shared__ float t[64][65];
    const int z = blockIdx.z;
    const float* src = z ? vw : kw;
    const int bf = blockIdx.x * 64, bd = blockIdx.y * 64;
    const int tid = threadIdx.x;
    #pragma unroll
    for (int i = 0; i < 16; ++i) {
        int idx = i * 256 + tid;
        int r = idx >> 6, c = idx & 63;
        t[r][c] = src[(size_t)(bf + r) * 512 + bd + c];
    }
    __syncthreads();
    #pragma unroll
    for (int i = 0; i < 16; ++i) {
        int idx = i * 256 + tid;
        int r = idx >> 6, c = idx & 63;
        _Float16 h = (_Float16)t[c][r];
        if (z == 0) {
            BkT[(size_t)(bd + r) * 512 + bf + c] = h;
        } else {
            BvT[(size_t)(bd + r) * 1024 + bf + c] = h;
            BvT[(size_t)(bd + r) * 1024 + 512 + bf + c] = h;
        }
    }
}

// bfih[j] = b_ih[j] + dot(w_ih[j,:], v_b)
__global__ __launch_bounds__(256) void bfih_kernel(
    const float* __restrict__ w_ih, const float* __restrict__ v_b,
    const float* __restrict__ b_ih, float* __restrict__ bfih) {
    int row = blockIdx.x * 4 + (threadIdx.x >> 6);
    int lane = threadIdx.x & 63;
    float c = 0.f;
    #pragma unroll
    for (int t = 0; t < 8; ++t) {
        int d = t * 64 + lane;
        c += w_ih[(size_t)row * 512 + d] * v_b[d];
    }
    c = waveReduceSum(c);
    if (lane == 0) bfih[row] = b_ih[row] + c;
}

// LN(inputs) -> Apack fp16 [65536][512]
__global__ __launch_bounds__(256) void pack_ln_single_kernel(
    const float* __restrict__ x, const float* __restrict__ g, const float* __restrict__ b,
    _Float16* __restrict__ Ap) {
    int wid = blockIdx.x * 4 + (threadIdx.x >> 6);
    int lane = threadIdx.x & 63;
    const float4* row4 = (const float4*)(x + (size_t)wid * Dd);
    float4 va = row4[lane * 2], vb = row4[lane * 2 + 1];
    float v[8] = {va.x, va.y, va.z, va.w, vb.x, vb.y, vb.z, vb.w};
    float s = 0.f, sq = 0.f;
    #pragma unroll
    for (int t = 0; t < 8; ++t) { s += v[t]; sq += v[t] * v[t]; }
    s = waveReduceSum(s);
    sq = waveReduceSum(sq);
    float m = s * (1.0f / Dd);
    float var = sq * (1.0f / Dd) - m * m;
    float rs = rsqrtf(var + LN_EPSf);
    const float4* g4 = (const float4*)g;
    const float4* b4 = (const float4*)b;
    float4 ga = g4[lane * 2], gb = g4[lane * 2 + 1];
    float4 ba = b4[lane * 2], bb = b4[lane * 2 + 1];
    float gg[8] = {ga.x, ga.y, ga.z, ga.w, gb.x, gb.y, gb.z, gb.w};
    float bbv[8] = {ba.x, ba.y, ba.z, ba.w, bb.x, bb.y, bb.z, bb.w};
    half8 o;
    #pragma unroll
    for (int t = 0; t < 8; ++t) o[t] = (_Float16)((v[t] - m) * rs * gg[t] + bbv[t]);
    *(half8*)(Ap + (size_t)wid * Dd + lane * 8) = o;
}

// slots init: slots fp32, A2 slot-rows (hi|lo), qh = LN(slots)*scale, cvec = qh.k_b;
// also zeroes the attn last-block counters (workspace is re-poisoned by harness).
__global__ __launch_bounds__(256) void slots_init_kernel(
    const float* __restrict__ noise, const float* __restrict__ mu,
    const float* __restrict__ ls, float* __restrict__ slots, _Float16* __restrict__ A2,
    const float* __restrict__ lns_g, const float* __restrict__ lns_b,
    _Float16* __restrict__ qh, const float* __restrict__ k_b, float* __restrict__ cvec,
    unsigned* __restrict__ cnt) {
    if (blockIdx.x == 0 && threadIdx.x < ITERS * Bb) cnt[threadIdx.x] = 0u;
    int row = blockIdx.x * 4 + (threadIdx.x >> 6);
    int lane = threadIdx.x & 63;
    float val[8];
    float s = 0.f, sq = 0.f;
    #pragma unroll
    for (int t = 0; t < 8; ++t) {
        int d = t * 64 + lane;
        float v = mu[d] + expf(ls[d]) * noise[(size_t)row * 512 + d];
        val[t] = v;
        s += v; sq += v * v;
        slots[(size_t)row * 512 + d] = v;
        _Float16 hi = (_Float16)v;
        A2[(size_t)(256 + row) * 1024 + d] = hi;
        A2[(size_t)(256 + row) * 1024 + 512 + d] = (_Float16)(v - (float)hi);
    }
    s = waveReduceSum(s);
    sq = waveReduceSum(sq);
    float m = s * (1.0f / Dd);
    float var = sq * (1.0f / Dd) - m * m;
    float rs = rsqrtf(var + LN_EPSf);
    float c = 0.f;
    #pragma unroll
    for (int t = 0; t < 8; ++t) {
        int d = t * 64 + lane;
        float qv = ((val[t] - m) * rs * lns_g[d] + lns_b[d]) * SCALEf;
        qh[(size_t)row * 512 + d] = (_Float16)qv;
        c += qv * k_b[d];
    }
    c = waveReduceSum(c);
    if (lane == 0) cvec[row] = c;
}

// ================= fused attention + last-block finalize =================
// dots = X.qk^T (hi|lo) + c; softmax over slots; W[slot,d] += attn*X (VALU f32).
// After writing rawp/sumsp: all-threads __threadfence (release) -> syncthreads ->
// tid0 atomicAdd cnt[it*32+b]; the 16th block acquires and reduces rawp/sumsp -> Whl
// (hi|lo). Counter zeroed each launch by slots_init (workspace poison-safe).
__global__ __launch_bounds__(256) void attn_kernel(
    const _Float16* __restrict__ Apack, const _Float16* __restrict__ Qk,
    const float* __restrict__ cvec,
    float* __restrict__ rawp, float* __restrict__ sumsp,
    _Float16* __restrict__ Whl, unsigned* __restrict__ cnt, int itc) {
    const int b = blockIdx.y, chunk = blockIdx.x;
    __shared__ _Float16 Xs[2][SUBT * 512];   // 64 KB
    __shared__ _Float16 aTh[SUBT][8];        // attn fp16 [token][slot]
    __shared__ float dlo[SUBT][8];           // lo-half dots
    __shared__ float sred[2][8];
    __shared__ int amlast;
    __shared__ float ssl[8];
    const int tid = threadIdx.x, w = tid >> 6, lane = tid & 63;
    const int lr = lane & 15, quad = lane >> 4;
    const int mt = w & 1, hl = w >> 1;
    const size_t tokbase = (size_t)b * Nn + chunk * 128;

    const float cv = cvec[b * 8 + (lr & 7)];
    const _Float16* qkrow = Qk + ((size_t)(b * 8 + (lr & 7)) << 10) + hl * 512;

    float2 w8[8];
    #pragma unroll
    for (int s = 0; s < 8; ++s) w8[s] = (float2){0.f, 0.f};
    float ssum_part = 0.f;
    const int d0 = w * 128 + lane * 2;
    const int pvslot = d0 >> 3, pvsub = d0 & 7;

    auto STAGE = [&](int st, int buf) {
        #pragma unroll
        for (int i = 0; i < 8; ++i) {
            int row = i * 4 + w;
            const _Float16* src = Apack + (tokbase + st * SUBT + row) * 512 +
                                  ((lane ^ (row & 7)) << 3);
            async_copy16(src, &Xs[buf][row * 512]);
        }
    };

    STAGE(0, 0);
    for (int st = 0; st < 4; ++st) {
        const int cur = st & 1;
        STAGE(st < 3 ? st + 1 : 3, cur ^ 1);
        asm volatile("s_waitcnt vmcnt(8)" ::: "memory");
        __syncthreads();
        const _Float16* Xc = &Xs[cur][0];
        // ---- QK: wave computes its m-tile x its qk-half ----
        f32x4 dots = (f32x4){0.f, 0.f, 0.f, 0.f};
        const int rr = mt * 16 + lr;
        #pragma unroll
        for (int ks = 0; ks < 16; ++ks) {
            half8 ax = *(const half8*)(Xc + rr * 512 +
                       ((((ks << 2) | quad) ^ (rr & 7)) << 3));
            half8 bq = *(const half8*)(qkrow + ks * 32 + quad * 8);
            dots = __builtin_amdgcn_mfma_f32_16x16x32_f16(ax, bq, dots, 0, 0, 0);
        }
        if (hl == 1 && lr < 8) {
            #pragma unroll
            for (int r = 0; r < 4; ++r) dlo[mt * 16 + quad * 4 + r][lr] = dots[r];
        }
        __syncthreads();
        if (hl == 0) {
            f32x4 d;
            #pragma unroll
            for (int r = 0; r < 4; ++r)
                d[r] = dots[r] + dlo[mt * 16 + quad * 4 + r][lr & 7] + cv;
            f32x4 mx = d;
            #pragma unroll
            for (int msk = 1; msk <= 4; msk <<= 1) {
                #pragma unroll
                for (int r = 0; r < 4; ++r) mx[r] = fmaxf(mx[r], __shfl_xor(mx[r], msk));
            }
            f32x4 p;
            #pragma unroll
            for (int r = 0; r < 4; ++r) p[r] = __expf(d[r] - mx[r]);
            f32x4 sm = p;
            #pragma unroll
            for (int msk = 1; msk <= 4; msk <<= 1) {
                #pragma unroll
                for (int r = 0; r < 4; ++r) sm[r] += __shfl_xor(sm[r], msk);
            }
            #pragma unroll
            for (int r = 0; r < 4; ++r) {
                _Float16 ph = (_Float16)(p[r] / sm[r] + EPSf);
                if (lr < 8) aTh[mt * 16 + quad * 4 + r][lr] = ph;
                ssum_part += (float)ph;
            }
        }
        __syncthreads();
        // ---- PV (all waves): W[slot][d-pair] += a * x, f32 acc ----
        #pragma unroll 4
        for (int t = 0; t < SUBT; ++t) {
            half8 aa = *(const half8*)&aTh[t][0];
            half2v xv = *(const half2v*)(Xc + t * 512 +
                        ((pvslot ^ (t & 7)) << 3) + pvsub);
            float x0 = (float)xv[0], x1 = (float)xv[1];
            #pragma unroll
            for (int s = 0; s < 8; ++s) {
                float av = (float)aa[s];
                w8[s].x += av * x0;
                w8[s].y += av * x1;
            }
        }
        __syncthreads();
    }
    asm volatile("s_waitcnt vmcnt(0)" ::: "memory");

    float* rp = rawp + ((size_t)chunk * Bb + b) * NS * Dd + d0;
    #pragma unroll
    for (int s = 0; s < 8; ++s) *(float2*)(rp + s * Dd) = w8[s];

    ssum_part += __shfl_xor(ssum_part, 16);
    ssum_part += __shfl_xor(ssum_part, 32);
    if (hl == 0 && lane < 8) sred[w][lane] = ssum_part;
    __syncthreads();
    if (tid < 8) sumsp[((size_t)chunk * Bb + b) * NS + tid] = sred[0][tid] + sred[1][tid];

    // ---- last-block finalize ----
    __threadfence();                        // release this block's rawp/sumsp
    __syncthreads();
    if (tid == 0) amlast = (atomicAdd(&cnt[itc * Bb + b], 1u) == CHUNKS - 1);
    __syncthreads();
    if (!amlast) return;
    __threadfence();                        // acquire other blocks' writes
    if (tid < 8) {
        float ss = 0.f;
        #pragma unroll
        for (int c = 0; c < CHUNKS; ++c) ss += sumsp[((size_t)c * Bb + b) * NS + tid];
        ssl[tid] = ss;
    }
    __syncthreads();
    #pragma unroll
    for (int t = 0; t < 16; ++t) {
        int idx = t * 256 + tid;            // 0..4095 = slot*512 + d
        int slot = idx >> 9, d = idx & 511;
        float acc = 0.f;
        #pragma unroll
        for (int c = 0; c < CHUNKS; ++c)
            acc += rawp[(((size_t)c * Bb + b) * NS + slot) * Dd + d];
        float val = acc / ssl[slot];
        _Float16 hi = (_Float16)val;
        Whl[(size_t)(b * 8 + slot) * 1024 + d] = hi;
        Whl[(size_t)(b * 8 + slot) * 1024 + 512 + d] = (_Float16)(val - (float)hi);
    }
}

// ================= 64-tile MFMA core (small gemms, LDS-staged) =================
__device__ __forceinline__ void hgemm64_core(
    const _Float16* __restrict__ A, const _Float16* __restrict__ Bw,
    int K2, f32x4 acc[2][2], _Float16* As, _Float16* Bs) {
    const int tid = threadIdx.x;
    const int w = tid >> 6, lane = tid & 63;
    const int r8 = lane >> 3, seg = lane & 7;
    const int lr = lane & 15, quad = lane >> 4;
    const int wm = w >> 1, wn = w & 1;
    for (int k0 = 0; k0 < K2; k0 += 64) {
        __syncthreads();
        #pragma unroll
        for (int p = 0; p < 2; ++p) {
            int grp = p * 4 + w;
            int row = grp * 8 + r8;
            async_copy16(A + (size_t)row * K2 + k0 + seg * 8, As + grp * 512);
            async_copy16(Bw + (size_t)row * K2 + k0 + seg * 8, Bs + grp * 512);
        }
        __syncthreads();
        #pragma unroll
        for (int kk = 0; kk < 2; ++kk) {
            half8 a[2], b[2];
            #pragma unroll
            for (int t = 0; t < 2; ++t) {
                a[t] = *(const half8*)(As + (wm * 32 + t * 16 + lr) * 64 + kk * 32 + quad * 8);
                b[t] = *(const half8*)(Bs + (wn * 32 + t * 16 + lr) * 64 + kk * 32 + quad * 8);
            }
            #pragma unroll
            for (int mt = 0; mt < 2; ++mt)
                #pragma unroll
                for (int nt = 0; nt < 2; ++nt)
                    acc[mt][nt] = __builtin_amdgcn_mfma_f32_16x16x32_f16(
                        a[mt], b[nt], acc[mt][nt], 0, 0, 0);
        }
    }
}

// generic 64-tile gemm. PACK: 0 = f32 C, 1 = hi|lo pack, 2 = dup pack.
template <int ACT, int PACK, int BIAS>
__global__ __launch_bounds__(256) void hgemm64_kernel(
    const _Float16* __restrict__ A, const _Float16* __restrict__ Bw,
    const float* __restrict__ bias, float* __restrict__ C, _Float16* __restrict__ P,
    int K2, int N, int Kp) {
    __shared__ _Float16 As[4096], Bs[4096];
    const int m0 = blockIdx.y * 64, n0 = blockIdx.x * 64;
    f32x4 acc[2][2];
    #pragma unroll
    for (int i = 0; i < 2; ++i)
        #pragma unroll
        for (int j = 0; j < 2; ++j) acc[i][j] = (f32x4){0.f, 0.f, 0.f, 0.f};
    hgemm64_core(A + (size_t)m0 * K2, Bw + (size_t)n0 * K2, K2, acc, As, Bs);
    const int tid = threadIdx.x;
    const int w = tid >> 6, lane = tid & 63;
    const int lr = lane & 15, quad = lane >> 4;
    const int wm = w >> 1, wn = w & 1;
    #pragma unroll
    for (int mt = 0; mt < 2; ++mt)
        #pragma unroll
        for (int nt = 0; nt < 2; ++nt) {
            int n = n0 + wn * 32 + nt * 16 + lr;
            float bv = BIAS ? bias[n] : 0.f;
            #pragma unroll
            for (int r = 0; r < 4; ++r) {
                int m = m0 + wm * 32 + mt * 16 + quad * 4 + r;
                float val = acc[mt][nt][r] + bv;
                if (ACT) val = gelu_exact(val);
                if (PACK) {
                    _Float16 hi = (_Float16)val;
                    P[(size_t)m * 2 * Kp + n] = hi;
                    P[(size_t)m * 2 * Kp + Kp + n] =
                        (PACK == 2) ? hi : (_Float16)(val - (float)hi);
                } else {
                    C[(size_t)m * N + n] = val;
                }
            }
        }
}

// ================= mega gemm: u | gi | gh in one launch (all from Whl / A2) =========
// blocks 0..31:   u  = Whl @ Bvd^T + v_b   -> ubuf, out0       (8n x 4m)
// blocks 32..127: gi = Whl @ BMih^T + bfih -> gi               (24n x 4m)
// blocks 128..223:gh = A2slot @ Bhh^T + b_hh -> gh             (24n x 4m)
__global__ __launch_bounds__(256) void mega_kernel(
    const _Float16* __restrict__ Whl, const _Float16* __restrict__ Bvd,
    const float* __restrict__ v_b, float* __restrict__ u, float* __restrict__ out0,
    const _Float16* __restrict__ BMih, const float* __restrict__ bfih,
    float* __restrict__ gi, const _Float16* __restrict__ A2,
    const _Float16* __restrict__ Bhh, const float* __restrict__ b_hh,
    float* __restrict__ gh) {
    __shared__ _Float16 As[4096], Bs[4096];
    const int bid = blockIdx.x;
    const _Float16* Ap; const _Float16* Bw; const float* bias;
    int m0, n0, role;
    if (bid < 32) {
        role = 0; m0 = (bid >> 3) * 64; n0 = (bid & 7) * 64;
        Ap = Whl + (size_t)m0 * 1024; Bw = Bvd + (size_t)n0 * 1024; bias = v_b;
    } else if (bid < 128) {
        role = 1; int idx = bid - 32; m0 = (idx / 24) * 64; n0 = (idx % 24) * 64;
        Ap = Whl + (size_t)m0 * 1024; Bw = BMih + (size_t)n0 * 1024; bias = bfih;
    } else {
        role = 2; int idx = bid - 128; m0 = (idx / 24) * 64; n0 = (idx % 24) * 64;
        Ap = A2 + (size_t)(256 + m0) * 1024; Bw = Bhh + (size_t)n0 * 1024; bias = b_hh;
    }
    f32x4 acc[2][2];
    #pragma unroll
    for (int i = 0; i < 2; ++i)
        #pragma unroll
        for (int j = 0; j < 2; ++j) acc[i][j] = (f32x4){0.f, 0.f, 0.f, 0.f};
    hgemm64_core(Ap, Bw, 1024, acc, As, Bs);
    const int tid = threadIdx.x;
    const int w = tid >> 6, lane = tid & 63;
    const int lr = lane & 15, quad = lane >> 4;
    const int wm = w >> 1, wn = w & 1;
    #pragma unroll
    for (int mt = 0; mt < 2; ++mt)
        #pragma unroll
        for (int nt = 0; nt < 2; ++nt) {
            int n = n0 + wn * 32 + nt * 16 + lr;
            float bv = bias[n];
            #pragma unroll
            for (int r = 0; r < 4; ++r) {
                int m = m0 + wm * 32 + mt * 16 + quad * 4 + r;
                float val = acc[mt][nt][r] + bv;
                if (role == 0) {
                    u[(size_t)m * 512 + n] = val;
                    out0[(size_t)m * 512 + n] = val;
                } else if (role == 1) {
                    gi[(size_t)m * 1536 + n] = val;
                } else {
                    gh[(size_t)m * 1536 + n] = val;
                }
            }
        }
}

// GRU elementwise; slots + A2 slot-rows; qh+cvec for next iter, or P1 on last
__global__ __launch_bounds__(256) void gru_elem_kernel(
    const float* __restrict__ gi, const float* __restrict__ gh,
    const float* __restrict__ u, float* __restrict__ slots, _Float16* __restrict__ A2,
    const float* __restrict__ lns_g, const float* __restrict__ lns_b,
    _Float16* __restrict__ qh, const float* __restrict__ k_b, float* __restrict__ cvec,
    const float* __restrict__ lnp_g, const float* __restrict__ lnp_b,
    _Float16* __restrict__ P1, int last) {
    int row = blockIdx.x * 4 + (threadIdx.x >> 6);
    int lane = threadIdx.x & 63;
    const float* gir = gi + (size_t)row * 1536;
    const float* ghr = gh + (size_t)row * 1536;
    float val[8];
    #pragma unroll
    for (int t = 0; t < 8; ++t) {
        int d = t * 64 + lane;
        float ir = gir[d], iz = gir[512 + d], in_ = gir[1024 + d];
        float hr = ghr[d], hz = ghr[512 + d], hn = ghr[1024 + d];
        float r = 1.0f / (1.0f + expf(-(ir + hr)));
        float z = 1.0f / (1.0f + expf(-(iz + hz)));
        float n = tanhf(in_ + r * hn);
        float h = slots[(size_t)row * 512 + d];
        float hnew = (1.0f - z) * n + z * h;
        float vv = u[(size_t)row * 512 + d] + hnew;
        val[t] = vv;
        slots[(size_t)row * 512 + d] = vv;
        _Float16 hi = (_Float16)vv;
        A2[(size_t)(256 + row) * 1024 + d] = hi;
        A2[(size_t)(256 + row) * 1024 + 512 + d] = (_Float16)(vv - (float)hi);
    }
    float s = 0.f, sq = 0.f;
    #pragma unroll
    for (int t = 0; t < 8; ++t) { s += val[t]; sq += val[t] * val[t]; }
    s = waveReduceSum(s);
    sq = waveReduceSum(sq);
    float m = s * (1.0f / Dd);
    float var = sq * (1.0f / Dd) - m * m;
    float rs = rsqrtf(var + LN_EPSf);
    if (!last) {
        float c = 0.f;
        #pragma unroll
        for (int t = 0; t < 8; ++t) {
            int d = t * 64 + lane;
            float qv = ((val[t] - m) * rs * lns_g[d] + lns_b[d]) * SCALEf;
            qh[(size_t)row * 512 + d] = (_Float16)qv;
            c += qv * k_b[d];
        }
        c = waveReduceSum(c);
        if (lane == 0) cvec[row] = c;
    } else {
        #pragma unroll
        for (int t = 0; t < 8; ++t) {
            int d = t * 64 + lane;
            float a = (val[t] - m) * rs * lnp_g[d] + lnp_b[d];
            _Float16 hi = (_Float16)a;
            P1[(size_t)row * 1024 + d] = hi;
            P1[(size_t)row * 1024 + 512 + d] = (_Float16)(a - (float)hi);
        }
    }
}

// ================= launch =================
extern "C" void kernel_launch(void* const* d_in, const int* in_sizes, int n_in,
                              void* d_out, int out_size, void* d_ws, size_t ws_size,
                              hipStream_t stream) {
    const float* inputs   = (const float*)d_in[0];
    const float* noise    = (const float*)d_in[1];
    const float* mu       = (const float*)d_in[2];
    const float* lsig     = (const float*)d_in[3];
    const float* k_w      = (const float*)d_in[4];
    const float* k_b      = (const float*)d_in[5];
    const float* v_w      = (const float*)d_in[6];
    const float* v_b      = (const float*)d_in[7];
    const float* w_ih     = (const float*)d_in[8];
    const float* w_hh     = (const float*)d_in[9];
    const float* b_ih     = (const float*)d_in[10];
    const float* b_hh     = (const float*)d_in[11];
    const float* ln_in_g  = (const float*)d_in[12];
    const float* ln_in_b  = (const float*)d_in[13];
    const float* ln_s_g   = (const float*)d_in[14];
    const float* ln_s_b   = (const float*)d_in[15];
    const float* ln_p_g   = (const float*)d_in[16];
    const float* ln_p_b   = (const float*)d_in[17];
    const float* mlp1_w   = (const float*)d_in[18];
    const float* mlp1_b   = (const float*)d_in[19];
    const float* mlp2_w   = (const float*)d_in[20];
    const float* mlp2_b   = (const float*)d_in[21];
    const float* mlp3_w   = (const float*)d_in[22];
    const float* mlp3_b   = (const float*)d_in[23];
    const float* mlp4_w   = (const float*)d_in[24];
    const float* mlp4_b   = (const float*)d_in[25];
    float* out0 = (float*)d_out;                 // updates [32,8,512]
    float* out1 = (float*)d_out + Bb * NS * Dd;  // s [32,8,256]

    char* wp = (char*)d_ws;
    auto alloc = [&](size_t bytes) -> void* {
        void* p = (void*)wp;
        wp += (bytes + 255) & ~(size_t)255;
        return p;
    };
    const size_t MR = (size_t)Bb * Nn;  // 65536
    _Float16* Apack = (_Float16*)alloc(MR * 512 * 2);              // 67 MB
    _Float16* Aih   = (_Float16*)alloc((size_t)1536 * 1024 * 2);   // w_ih hi|lo
    _Float16* Bhh   = (_Float16*)alloc((size_t)1536 * 1024 * 2);
    _Float16* Bm1   = (_Float16*)alloc((size_t)1024 * 1024 * 2);
    _Float16* Bm2   = (_Float16*)alloc((size_t)1024 * 2048 * 2);
    _Float16* Bm3   = (_Float16*)alloc((size_t)512 * 2048 * 2);
    _Float16* Bm4   = (_Float16*)alloc((size_t)256 * 1024 * 2);
    _Float16* Bvd   = (_Float16*)alloc((size_t)512 * 1024 * 2);    // v_w dup'd
    _Float16* BkT   = (_Float16*)alloc((size_t)512 * 512 * 2);     // k_w^T fp16
    _Float16* BvT   = (_Float16*)alloc((size_t)512 * 1024 * 2);    // v_w^T dup'd
    _Float16* BMih  = (_Float16*)alloc((size_t)1536 * 1024 * 2);   // (w_ih@v_w) dup'd
    float* bfih     = (float*)alloc((size_t)1536 * 4);
    unsigned* cnt   = (unsigned*)alloc((size_t)ITERS * Bb * 4);
    float* slots    = (float*)alloc((size_t)Bb * NS * Dd * 4);
    _Float16* qh    = (_Float16*)alloc((size_t)Bb * NS * Dd * 2);
    float* cvec     = (float*)alloc((size_t)Bb * NS * 4);
    _Float16* Qk    = (_Float16*)alloc((size_t)256 * 1024 * 2);    // qk hi|lo
    float* rawp     = (float*)alloc((size_t)CHUNKS * Bb * NS * Dd * 4);  // 8 MB
    float* sumsp    = (float*)alloc((size_t)CHUNKS * Bb * NS * 4);
    _Float16* Whl   = (_Float16*)alloc((size_t)256 * 1024 * 2);    // W hi|lo
    float* ubuf     = (float*)alloc((size_t)Bb * NS * Dd * 4);
    float* gi       = (float*)alloc((size_t)Bb * NS * 1536 * 4);
    float* gh       = (float*)alloc((size_t)Bb * NS * 1536 * 4);
    _Float16* A2    = (_Float16*)alloc((size_t)512 * 1024 * 2);
    _Float16* P1    = (_Float16*)alloc((size_t)256 * 1024 * 2);
    _Float16* P2    = (_Float16*)alloc((size_t)256 * 2048 * 2);
    _Float16* P3    = (_Float16*)alloc((size_t)256 * 2048 * 2);
    _Float16* P4    = (_Float16*)alloc((size_t)256 * 1024 * 2);

    // ---- prep ----
    megapack_kernel<<<15872, 256, 0, stream>>>(
        w_ih, w_hh, mlp1_w, mlp2_w, mlp3_w, mlp4_w, v_w,
        Aih, Bhh, Bm1, Bm2, Bm3, Bm4, Bvd);
    twk_kernel<<<dim3(8, 8, 2), 256, 0, stream>>>(k_w, v_w, BkT, BvT);
    pack_ln_single_kernel<<<MR / 4, 256, 0, stream>>>(inputs, ln_in_g, ln_in_b, Apack);
    slots_init_kernel<<<64, 256, 0, stream>>>(noise, mu, lsig, slots, A2,
                                              ln_s_g, ln_s_b, qh, k_b, cvec, cnt);
    bfih_kernel<<<384, 256, 0, stream>>>(w_ih, v_b, b_ih, bfih);
    // Mih = w_ih @ v_w  (hi|lo A x dup B), packed dup for the gi gemm
    hgemm64_kernel<0, 2, 0><<<dim3(8, 24), 256, 0, stream>>>(
        Aih, BvT, nullptr, nullptr, BMih, 1024, 512, 512);

    for (int it = 0; it < ITERS; ++it) {
        hgemm64_kernel<0, 1, 0><<<dim3(8, 4), 256, 0, stream>>>(
            qh, BkT, nullptr, nullptr, Qk, 512, 512, 512);
        attn_kernel<<<dim3(CHUNKS, Bb), 256, 0, stream>>>(
            Apack, Qk, cvec, rawp, sumsp, Whl, cnt, it);
        mega_kernel<<<224, 256, 0, stream>>>(
            Whl, Bvd, v_b, ubuf, out0, BMih, bfih, gi, A2, Bhh, b_hh, gh);
        gru_elem_kernel<<<64, 256, 0, stream>>>(gi, gh, ubuf, slots, A2,
                                                ln_s_g, ln_s_b, qh, k_b, cvec,
                                                ln_p_g, ln_p_b, P1, it == ITERS - 1 ? 1 : 0);
    }

    // ---- output MLP ----
    hgemm64_kernel<1, 1, 1><<<dim3(16, 4), 256, 0, stream>>>(P1, Bm1, mlp1_b, nullptr, P2, 1024, 1024, 1024);
    hgemm64_kernel<1, 1, 1><<<dim3(16, 4), 256, 0, stream>>>(P2, Bm2, mlp2_b, nullptr, P3, 2048, 1024, 1024);
    hgemm64_kernel<1, 1, 1><<<dim3(8, 4), 256, 0, stream>>>(P3, Bm3, mlp3_b, nullptr, P4, 2048, 512, 512);
    hgemm64_kernel<0, 0, 1><<<dim3(4, 4), 256, 0, stream>>>(P4, Bm4, mlp4_b, out1, nullptr, 1024, 256, 256);
}